// Round 1
// baseline (25589.897 us; speedup 1.0000x reference)
//
#include <hip/hip_runtime.h>
#include <hip/hip_bf16.h>

// Problem constants
#define BB   256   // batch
#define SS   128   // seq len
#define HH   512   // hidden
#define G4   2048  // 4*H
#define IN_  414   // F*N input features
#define NN   207
#define OUT_ 414   // 2*N

// ---------------------------------------------------------------------------
// Transpose x [B, F, N, S] -> xs [S, B, IN] (row-major, stride IN)
// x flat index: (b*414 + i)*128 + s  with i = f*207+n
// ---------------------------------------------------------------------------
__global__ __launch_bounds__(256) void transpose_x_kernel(
    const float* __restrict__ x, float* __restrict__ xs)
{
    int idx = blockIdx.x * 256 + threadIdx.x;   // over S*B*IN
    const int total = SS * BB * IN_;
    if (idx >= total) return;
    int i = idx % IN_;
    int t = idx / IN_;
    int b = t % BB;
    int s = t / BB;
    xs[idx] = x[(b * IN_ + i) * SS + s];
}

// ---------------------------------------------------------------------------
// One LSTM timestep for all 256 batches:
//   g[b, j] = bias[j] + xin[b,:] @ w_ih[j,:] + h_prev[b,:] @ w_hh[j,:]
//   gates (i,f,g,o at j, j+512, j+1024, j+1536), update c, write h.
// Tile: 32 batch x (16 jj x 4 gates). Block = 256 threads, each thread owns
// 2 batches x 1 jj x all 4 gates -> epilogue needs no cross-thread comm.
// Grid: (256/32, 512/16) = (8, 32) = 256 WGs.
// ---------------------------------------------------------------------------
__global__ __launch_bounds__(256) void lstm_step_kernel(
    const float* __restrict__ xin, int Kin,          // [B, Kin] row-major
    const float* __restrict__ w_ih,                  // [2048, Kin]
    const float* __restrict__ w_hh,                  // [2048, 512]
    const float* __restrict__ b_ih,
    const float* __restrict__ b_hh,
    const float* __restrict__ h_prev,                // [B, 512] or null
    float* __restrict__ h_out,                       // [B, 512]
    float* __restrict__ c_state,                     // [B, 512]
    int first)
{
    __shared__ float As[32][33];   // 32 batch x 32 k
    __shared__ float Bs[64][33];   // 64 (gate*16+jj) rows x 32 k

    const int tid  = threadIdx.x;
    const int jj_t = tid & 15;     // 0..15
    const int bp   = tid >> 4;     // 0..15 -> batches 2*bp, 2*bp+1
    const int bb   = blockIdx.x * 32;
    const int jj0  = blockIdx.y * 16;

    float acc[2][4];
#pragma unroll
    for (int u = 0; u < 2; ++u)
#pragma unroll
        for (int v = 0; v < 4; ++v) acc[u][v] = 0.f;

    for (int phase = 0; phase < 2; ++phase) {
        if (phase && first) break;   // h_prev == 0 at s==0
        const float* Aq = phase ? h_prev : xin;
        const float* Wq = phase ? w_hh : w_ih;
        const int K    = phase ? HH : Kin;

        for (int k0 = 0; k0 < K; k0 += 32) {
            __syncthreads();
            // stage A: 32x32, 4 elems/thread, coalesced over k
#pragma unroll
            for (int u = 0; u < 4; ++u) {
                int idx = u * 256 + tid;
                int bl = idx >> 5, kk = idx & 31;
                int k = k0 + kk;
                As[bl][kk] = (k < K) ? Aq[(size_t)(bb + bl) * K + k] : 0.f;
            }
            // stage B: 64x32, 8 elems/thread, coalesced over k
#pragma unroll
            for (int u = 0; u < 8; ++u) {
                int idx = u * 256 + tid;
                int r = idx >> 5, kk = idx & 31;
                int gate = r >> 4, jt = r & 15;
                int j = gate * HH + jj0 + jt;
                int k = k0 + kk;
                Bs[r][kk] = (k < K) ? Wq[(size_t)j * K + k] : 0.f;
            }
            __syncthreads();
#pragma unroll
            for (int kk = 0; kk < 32; ++kk) {
                float a0 = As[bp * 2][kk];
                float a1 = As[bp * 2 + 1][kk];
                float w0 = Bs[jj_t][kk];
                float w1 = Bs[16 + jj_t][kk];
                float w2 = Bs[32 + jj_t][kk];
                float w3 = Bs[48 + jj_t][kk];
                acc[0][0] += a0 * w0;  acc[0][1] += a0 * w1;
                acc[0][2] += a0 * w2;  acc[0][3] += a0 * w3;
                acc[1][0] += a1 * w0;  acc[1][1] += a1 * w1;
                acc[1][2] += a1 * w2;  acc[1][3] += a1 * w3;
            }
        }
    }

    // epilogue: gates + cell update
    const int jj = jj0 + jj_t;
    const float bi = b_ih[jj]            + b_hh[jj];
    const float bf = b_ih[HH + jj]       + b_hh[HH + jj];
    const float bg = b_ih[2 * HH + jj]   + b_hh[2 * HH + jj];
    const float bo = b_ih[3 * HH + jj]   + b_hh[3 * HH + jj];
#pragma unroll
    for (int u = 0; u < 2; ++u) {
        const int b = bb + bp * 2 + u;
        float xi = acc[u][0] + bi;
        float xf = acc[u][1] + bf;
        float xg = acc[u][2] + bg;
        float xo = acc[u][3] + bo;
        float ig = 1.f / (1.f + __expf(-xi));
        float fg = 1.f / (1.f + __expf(-xf));
        float gg = tanhf(xg);
        float og = 1.f / (1.f + __expf(-xo));
        const int ci = b * HH + jj;
        float cold = first ? 0.f : c_state[ci];
        float cn = fg * cold + ig * gg;
        float hn = og * tanhf(cn);
        c_state[ci] = cn;
        h_out[ci]   = hn;
    }
}

// ---------------------------------------------------------------------------
// FC: out[b, oc, n, s] = fc_b[o] + h2[(s*B+b), :] @ fc_w[o, :],  o = oc*207+n
// Tile: 32 m x 64 o, each thread 2 m x 4 o. Grid: (1024, 7).
// ---------------------------------------------------------------------------
__global__ __launch_bounds__(256) void fc_kernel(
    const float* __restrict__ h2,     // [S*B, 512]
    const float* __restrict__ fc_w,   // [414, 512]
    const float* __restrict__ fc_b,   // [414]
    float* __restrict__ out)          // [B, 2, 207, 128]
{
    __shared__ float As[32][33];
    __shared__ float Bs[64][33];

    const int tid = threadIdx.x;
    const int ot  = tid & 15;
    const int bp  = tid >> 4;
    const int mb  = blockIdx.x * 32;
    const int o0  = blockIdx.y * 64;

    float acc[2][4];
#pragma unroll
    for (int u = 0; u < 2; ++u)
#pragma unroll
        for (int v = 0; v < 4; ++v) acc[u][v] = 0.f;

    for (int k0 = 0; k0 < HH; k0 += 32) {
        __syncthreads();
#pragma unroll
        for (int u = 0; u < 4; ++u) {
            int idx = u * 256 + tid;
            int ml = idx >> 5, kk = idx & 31;
            As[ml][kk] = h2[(size_t)(mb + ml) * HH + k0 + kk];
        }
#pragma unroll
        for (int u = 0; u < 8; ++u) {
            int idx = u * 256 + tid;
            int r = idx >> 5, kk = idx & 31;
            int o = o0 + r;
            Bs[r][kk] = (o < OUT_) ? fc_w[(size_t)o * HH + k0 + kk] : 0.f;
        }
        __syncthreads();
#pragma unroll
        for (int kk = 0; kk < 32; ++kk) {
            float a0 = As[bp * 2][kk];
            float a1 = As[bp * 2 + 1][kk];
            float w0 = Bs[ot][kk];
            float w1 = Bs[16 + ot][kk];
            float w2 = Bs[32 + ot][kk];
            float w3 = Bs[48 + ot][kk];
            acc[0][0] += a0 * w0;  acc[0][1] += a0 * w1;
            acc[0][2] += a0 * w2;  acc[0][3] += a0 * w3;
            acc[1][0] += a1 * w0;  acc[1][1] += a1 * w1;
            acc[1][2] += a1 * w2;  acc[1][3] += a1 * w3;
        }
    }

#pragma unroll
    for (int u = 0; u < 2; ++u) {
        const int m = mb + bp * 2 + u;
        const int s = m >> 8;        // m = s*256 + b
        const int b = m & 255;
#pragma unroll
        for (int v = 0; v < 4; ++v) {
            const int o = o0 + v * 16 + ot;
            if (o < OUT_) {
                const int oc = (o < NN) ? 0 : 1;
                const int n  = (o < NN) ? o : o - NN;
                out[(((size_t)b * 2 + oc) * NN + n) * SS + s] = acc[u][v] + fc_b[o];
            }
        }
    }
}

// ---------------------------------------------------------------------------
extern "C" void kernel_launch(void* const* d_in, const int* in_sizes, int n_in,
                              void* d_out, int out_size, void* d_ws, size_t ws_size,
                              hipStream_t stream)
{
    const float* x     = (const float*)d_in[0];
    const float* w_ih0 = (const float*)d_in[1];
    const float* w_hh0 = (const float*)d_in[2];
    const float* b_ih0 = (const float*)d_in[3];
    const float* b_hh0 = (const float*)d_in[4];
    const float* w_ih1 = (const float*)d_in[5];
    const float* w_hh1 = (const float*)d_in[6];
    const float* b_ih1 = (const float*)d_in[7];
    const float* b_hh1 = (const float*)d_in[8];
    const float* fc_w  = (const float*)d_in[9];
    const float* fc_b  = (const float*)d_in[10];
    float* out = (float*)d_out;

    float* ws = (float*)d_ws;
    float* xs   = ws;                                  // S*B*IN  = 13,565,952
    float* h1   = xs + (size_t)SS * BB * IN_;          // S*B*H   = 16,777,216
    float* h2   = h1 + (size_t)SS * BB * HH;           // S*B*H   = 16,777,216
    float* cbuf = h2 + (size_t)SS * BB * HH;           // B*H     = 131,072

    // 1) transpose x -> xs [S, B, IN]
    {
        const int total = SS * BB * IN_;
        transpose_x_kernel<<<(total + 255) / 256, 256, 0, stream>>>(x, xs);
    }

    // 2) layer 0: 128 sequential steps (K = 414 input + 512 recurrent)
    for (int s = 0; s < SS; ++s) {
        lstm_step_kernel<<<dim3(8, 32), 256, 0, stream>>>(
            xs + (size_t)s * BB * IN_, IN_,
            w_ih0, w_hh0, b_ih0, b_hh0,
            s ? h1 + (size_t)(s - 1) * BB * HH : nullptr,
            h1 + (size_t)s * BB * HH,
            cbuf, s == 0 ? 1 : 0);
    }

    // 3) layer 1: 128 sequential steps (K = 512 input + 512 recurrent)
    for (int s = 0; s < SS; ++s) {
        lstm_step_kernel<<<dim3(8, 32), 256, 0, stream>>>(
            h1 + (size_t)s * BB * HH, HH,
            w_ih1, w_hh1, b_ih1, b_hh1,
            s ? h2 + (size_t)(s - 1) * BB * HH : nullptr,
            h2 + (size_t)s * BB * HH,
            cbuf, s == 0 ? 1 : 0);
    }

    // 4) FC + output transpose
    fc_kernel<<<dim3(SS * BB / 32, (OUT_ + 63) / 64), 256, 0, stream>>>(
        h2, fc_w, fc_b, out);
}

// Round 2
// 9943.232 us; speedup vs baseline: 2.5736x; 2.5736x over previous
//
#include <hip/hip_runtime.h>
#include <hip/hip_bf16.h>
#include <hip/hip_cooperative_groups.h>

namespace cg = cooperative_groups;

// Problem constants
#define BB   256   // batch
#define SS   128   // seq len
#define HH   512   // hidden
#define IN_  414   // F*N input features
#define INP  416   // padded input features (multiple of 32)
#define NN   207
#define OUT_ 414   // 2*N

#define LDS_STRIDE 68   // 64 cols + pad; 272B row stride (16B aligned, bank-shifts rows)

// ---------------------------------------------------------------------------
// xpad [S][B][416]: transpose of x [B,F,N,S] with zero pad at cols 414,415
// ---------------------------------------------------------------------------
__global__ __launch_bounds__(256) void transpose_pad_x_kernel(
    const float* __restrict__ x, float* __restrict__ xpad)
{
    int idx = blockIdx.x * 256 + threadIdx.x;
    const int total = SS * BB * INP;
    if (idx >= total) return;
    int i = idx % INP;
    int t = idx / INP;
    int b = t % BB;
    int s = t / BB;
    xpad[idx] = (i < IN_) ? x[(b * IN_ + i) * SS + s] : 0.f;
}

// wih0p [2048][416] zero-padded copy of w_ih0 [2048][414]
__global__ __launch_bounds__(256) void pad_wih0_kernel(
    const float* __restrict__ w, float* __restrict__ wp)
{
    int idx = blockIdx.x * 256 + threadIdx.x;
    const int total = 4 * HH * INP;
    if (idx >= total) return;
    int k = idx % INP;
    int j = idx / INP;
    wp[idx] = (k < IN_) ? w[j * IN_ + k] : 0.f;
}

// ---------------------------------------------------------------------------
// One GEMM phase: acc[4][4] += A_tile[64b x K] * W[4 gates x 16 jj x K]^T
// LDS k-major: As[kk][64 b cols], Ws[kk][64 cols = jj*4+gate].
// Per-thread: 4 batches (av) x 4 gates (wv) of one jj. Register prefetch,
// single LDS buffer, 2 barriers per 32-k tile.
// ---------------------------------------------------------------------------
__device__ __forceinline__ void gemm_phase(
    const float* __restrict__ Ab, int sA,      // A base (already offset to bb), row stride
    const float* __restrict__ Wb, int sW,      // weight base [4H x sW]
    int jj0, int K, int tid, int tx, int ty,
    float* __restrict__ As, float* __restrict__ Ws,
    float acc[4][4])
{
    const int bl   = tid >> 3;          // 0..31  (A col / W col, first half)
    const int kq8  = (tid & 7) * 4;     // k offset within tile
    const int bl1  = bl + 32;           // second half 32..63
    // W column -> weight row mapping: col = u16*4 + gate
    const int wrow0 = (bl  & 3) * HH + jj0 + (bl  >> 2);
    const int wrow1 = (bl1 & 3) * HH + jj0 + (bl1 >> 2);

    float4 a0, a1, w0, w1;
    a0 = *(const float4*)(Ab + (size_t)bl   * sA + kq8);
    a1 = *(const float4*)(Ab + (size_t)bl1  * sA + kq8);
    w0 = *(const float4*)(Wb + (size_t)wrow0 * sW + kq8);
    w1 = *(const float4*)(Wb + (size_t)wrow1 * sW + kq8);

    const int nt = K >> 5;
    for (int kt = 0; kt < nt; ++kt) {
        __syncthreads();   // previous tile's LDS reads done
        As[(kq8 + 0) * LDS_STRIDE + bl ] = a0.x;
        As[(kq8 + 1) * LDS_STRIDE + bl ] = a0.y;
        As[(kq8 + 2) * LDS_STRIDE + bl ] = a0.z;
        As[(kq8 + 3) * LDS_STRIDE + bl ] = a0.w;
        As[(kq8 + 0) * LDS_STRIDE + bl1] = a1.x;
        As[(kq8 + 1) * LDS_STRIDE + bl1] = a1.y;
        As[(kq8 + 2) * LDS_STRIDE + bl1] = a1.z;
        As[(kq8 + 3) * LDS_STRIDE + bl1] = a1.w;
        Ws[(kq8 + 0) * LDS_STRIDE + bl ] = w0.x;
        Ws[(kq8 + 1) * LDS_STRIDE + bl ] = w0.y;
        Ws[(kq8 + 2) * LDS_STRIDE + bl ] = w0.z;
        Ws[(kq8 + 3) * LDS_STRIDE + bl ] = w0.w;
        Ws[(kq8 + 0) * LDS_STRIDE + bl1] = w1.x;
        Ws[(kq8 + 1) * LDS_STRIDE + bl1] = w1.y;
        Ws[(kq8 + 2) * LDS_STRIDE + bl1] = w1.z;
        Ws[(kq8 + 3) * LDS_STRIDE + bl1] = w1.w;
        __syncthreads();

        if (kt + 1 < nt) {   // prefetch next tile while computing this one
            const int k0 = (kt + 1) << 5;
            a0 = *(const float4*)(Ab + (size_t)bl   * sA + k0 + kq8);
            a1 = *(const float4*)(Ab + (size_t)bl1  * sA + k0 + kq8);
            w0 = *(const float4*)(Wb + (size_t)wrow0 * sW + k0 + kq8);
            w1 = *(const float4*)(Wb + (size_t)wrow1 * sW + k0 + kq8);
        }

#pragma unroll
        for (int kk = 0; kk < 32; ++kk) {
            float4 av = *(const float4*)(As + kk * LDS_STRIDE + 4 * ty);
            float4 wv = *(const float4*)(Ws + kk * LDS_STRIDE + 4 * tx);
            acc[0][0] += av.x * wv.x; acc[0][1] += av.x * wv.y;
            acc[0][2] += av.x * wv.z; acc[0][3] += av.x * wv.w;
            acc[1][0] += av.y * wv.x; acc[1][1] += av.y * wv.y;
            acc[1][2] += av.y * wv.z; acc[1][3] += av.y * wv.w;
            acc[2][0] += av.z * wv.x; acc[2][1] += av.z * wv.y;
            acc[2][2] += av.z * wv.z; acc[2][3] += av.z * wv.w;
            acc[3][0] += av.w * wv.x; acc[3][1] += av.w * wv.y;
            acc[3][2] += av.w * wv.z; acc[3][3] += av.w * wv.w;
        }
    }
}

// ---------------------------------------------------------------------------
// Persistent cooperative kernel: both layers, all timesteps, pipelined.
// Grid = 256 WGs x 256 thr. WG 0..127: layer 0; 128..255: layer 1 (lags 1 step).
// Each WG: tile 64 batch x (16 jj x 4 gates). c-state lives in registers.
// ---------------------------------------------------------------------------
__global__ __launch_bounds__(256, 1) void lstm_persist_kernel(
    const float* __restrict__ xpad,    // [S][B][416]
    const float* __restrict__ wih0p,   // [2048][416]
    const float* __restrict__ whh0,    // [2048][512]
    const float* __restrict__ bih0, const float* __restrict__ bhh0,
    const float* __restrict__ wih1,    // [2048][512]
    const float* __restrict__ whh1,    // [2048][512]
    const float* __restrict__ bih1, const float* __restrict__ bhh1,
    float* __restrict__ h1ring,        // [2][B][512]
    float* __restrict__ h2)            // [S][B][512]
{
    cg::grid_group grid = cg::this_grid();
    __shared__ float As[32 * LDS_STRIDE];
    __shared__ float Ws[32 * LDS_STRIDE];

    const int tid = threadIdx.x;
    const int tx = tid & 15;           // jj offset 0..15
    const int ty = tid >> 4;           // batch group 0..15
    const int wg = blockIdx.x;
    const int layer = wg >> 7;
    const int r = wg & 127;
    const int bb  = (r >> 5) * 64;     // 4 batch blocks of 64
    const int jj0 = (r & 31) * 16;     // 32 jj blocks of 16
    const int jj  = jj0 + tx;

    const float* bi_p = layer ? bih1 : bih0;
    const float* bh_p = layer ? bhh1 : bhh0;
    float bsum[4];
#pragma unroll
    for (int g = 0; g < 4; ++g) bsum[g] = bi_p[g * HH + jj] + bh_p[g * HH + jj];

    const float* wih = layer ? wih1 : wih0p;
    const int    sIH = layer ? HH   : INP;
    const float* whh = layer ? whh1 : whh0;

    float c[4] = {0.f, 0.f, 0.f, 0.f};

    for (int t = 0; t <= SS; ++t) {
        const bool active = layer ? (t >= 1) : (t < SS);
        if (active) {
            const int s = layer ? (t - 1) : t;   // this layer's timestep index

            // input-projection phase
            const float* Ax;
            int Kx;
            if (layer == 0) { Ax = xpad + (size_t)t * BB * INP + (size_t)bb * INP; Kx = INP; }
            else            { Ax = h1ring + (size_t)((t - 1) & 1) * BB * HH + (size_t)bb * HH; Kx = HH; }

            float acc[4][4];
#pragma unroll
            for (int u = 0; u < 4; ++u)
#pragma unroll
                for (int v = 0; v < 4; ++v) acc[u][v] = 0.f;

            gemm_phase(Ax, sIH == HH ? HH : INP, wih, sIH, jj0, Kx, tid, tx, ty, As, Ws, acc);

            // recurrent phase (h_prev == 0 on this layer's first step)
            const bool haveH = (s >= 1);
            if (haveH) {
                const float* Ah = layer
                    ? (h2 + (size_t)(s - 1) * BB * HH + (size_t)bb * HH)
                    : (h1ring + (size_t)((t - 1) & 1) * BB * HH + (size_t)bb * HH);
                gemm_phase(Ah, HH, whh, HH, jj0, HH, tid, tx, ty, As, Ws, acc);
            }

            // epilogue: gates, cell update (c in registers), h write
            float* hout = layer
                ? (h2 + (size_t)s * BB * HH)
                : (h1ring + (size_t)(t & 1) * BB * HH);
#pragma unroll
            for (int u = 0; u < 4; ++u) {
                const int b = bb + 4 * ty + u;
                float xi = acc[u][0] + bsum[0];
                float xf = acc[u][1] + bsum[1];
                float xg = acc[u][2] + bsum[2];
                float xo = acc[u][3] + bsum[3];
                float ig = 1.f / (1.f + __expf(-xi));
                float fg = 1.f / (1.f + __expf(-xf));
                float gg = tanhf(xg);
                float og = 1.f / (1.f + __expf(-xo));
                float cn = fg * c[u] + ig * gg;
                c[u] = cn;
                hout[(size_t)b * HH + jj] = og * tanhf(cn);
            }
        }
        grid.sync();
    }
}

// ---------------------------------------------------------------------------
// FC: out[b, oc, n, s] = fc_b[o] + h2[(s*B+b), :] @ fc_w[o, :]
// (unchanged from round 1 — known correct; optimize next round if it matters)
// ---------------------------------------------------------------------------
__global__ __launch_bounds__(256) void fc_kernel(
    const float* __restrict__ h2,     // [S*B, 512]
    const float* __restrict__ fc_w,   // [414, 512]
    const float* __restrict__ fc_b,   // [414]
    float* __restrict__ out)          // [B, 2, 207, 128]
{
    __shared__ float As2[32][33];
    __shared__ float Bs2[64][33];

    const int tid = threadIdx.x;
    const int ot  = tid & 15;
    const int bp  = tid >> 4;
    const int mb  = blockIdx.x * 32;
    const int o0  = blockIdx.y * 64;

    float acc[2][4];
#pragma unroll
    for (int u = 0; u < 2; ++u)
#pragma unroll
        for (int v = 0; v < 4; ++v) acc[u][v] = 0.f;

    for (int k0 = 0; k0 < HH; k0 += 32) {
        __syncthreads();
#pragma unroll
        for (int u = 0; u < 4; ++u) {
            int idx = u * 256 + tid;
            int ml = idx >> 5, kk = idx & 31;
            As2[ml][kk] = h2[(size_t)(mb + ml) * HH + k0 + kk];
        }
#pragma unroll
        for (int u = 0; u < 8; ++u) {
            int idx = u * 256 + tid;
            int rr = idx >> 5, kk = idx & 31;
            int o = o0 + rr;
            Bs2[rr][kk] = (o < OUT_) ? fc_w[(size_t)o * HH + k0 + kk] : 0.f;
        }
        __syncthreads();
#pragma unroll
        for (int kk = 0; kk < 32; ++kk) {
            float a0 = As2[bp * 2][kk];
            float a1 = As2[bp * 2 + 1][kk];
            float w0 = Bs2[ot][kk];
            float w1 = Bs2[16 + ot][kk];
            float w2 = Bs2[32 + ot][kk];
            float w3 = Bs2[48 + ot][kk];
            acc[0][0] += a0 * w0;  acc[0][1] += a0 * w1;
            acc[0][2] += a0 * w2;  acc[0][3] += a0 * w3;
            acc[1][0] += a1 * w0;  acc[1][1] += a1 * w1;
            acc[1][2] += a1 * w2;  acc[1][3] += a1 * w3;
        }
    }

#pragma unroll
    for (int u = 0; u < 2; ++u) {
        const int m = mb + bp * 2 + u;
        const int s = m >> 8;
        const int b = m & 255;
#pragma unroll
        for (int v = 0; v < 4; ++v) {
            const int o = o0 + v * 16 + ot;
            if (o < OUT_) {
                const int oc = (o < NN) ? 0 : 1;
                const int n  = (o < NN) ? o : o - NN;
                out[(((size_t)b * 2 + oc) * NN + n) * SS + s] = acc[u][v] + fc_b[o];
            }
        }
    }
}

// ---------------------------------------------------------------------------
extern "C" void kernel_launch(void* const* d_in, const int* in_sizes, int n_in,
                              void* d_out, int out_size, void* d_ws, size_t ws_size,
                              hipStream_t stream)
{
    const float* x     = (const float*)d_in[0];
    const float* w_ih0 = (const float*)d_in[1];
    const float* w_hh0 = (const float*)d_in[2];
    const float* b_ih0 = (const float*)d_in[3];
    const float* b_hh0 = (const float*)d_in[4];
    const float* w_ih1 = (const float*)d_in[5];
    const float* w_hh1 = (const float*)d_in[6];
    const float* b_ih1 = (const float*)d_in[7];
    const float* b_hh1 = (const float*)d_in[8];
    const float* fc_w  = (const float*)d_in[9];
    const float* fc_b  = (const float*)d_in[10];
    float* out = (float*)d_out;

    float* ws = (float*)d_ws;
    float* xpad   = ws;                                   // S*B*416 = 13,631,488
    float* wih0p  = xpad  + (size_t)SS * BB * INP;        // 2048*416 = 851,968
    float* h1ring = wih0p + (size_t)4 * HH * INP;         // 2*B*H   = 262,144
    float* h2     = h1ring + (size_t)2 * BB * HH;         // S*B*H   = 16,777,216

    // 1) transpose+pad x, pad w_ih0
    {
        const int total = SS * BB * INP;
        transpose_pad_x_kernel<<<(total + 255) / 256, 256, 0, stream>>>(x, xpad);
        const int totw = 4 * HH * INP;
        pad_wih0_kernel<<<(totw + 255) / 256, 256, 0, stream>>>(w_ih0, wih0p);
    }

    // 2) persistent cooperative LSTM (both layers, pipelined, 129 grid syncs)
    {
        void* args[] = {
            (void*)&xpad, (void*)&wih0p, (void*)&w_hh0,
            (void*)&b_ih0, (void*)&b_hh0,
            (void*)&w_ih1, (void*)&w_hh1, (void*)&b_ih1, (void*)&b_hh1,
            (void*)&h1ring, (void*)&h2
        };
        hipLaunchCooperativeKernel((void*)lstm_persist_kernel,
                                   dim3(256), dim3(256), args, 0, stream);
    }

    // 3) FC + output transpose
    fc_kernel<<<dim3(SS * BB / 32, (OUT_ + 63) / 64), 256, 0, stream>>>(
        h2, fc_w, fc_b, out);
}

// Round 3
// 9816.547 us; speedup vs baseline: 2.6068x; 1.0129x over previous
//
#include <hip/hip_runtime.h>
#include <hip/hip_bf16.h>
#include <hip/hip_cooperative_groups.h>

namespace cg = cooperative_groups;

typedef _Float16 f16;
typedef _Float16 half8 __attribute__((ext_vector_type(8)));
typedef float float4_ __attribute__((ext_vector_type(4)));

#define BB   256
#define SS   128
#define HH   512
#define IN_  414
#define INP  416
#define NN   207
#define OUT_ 414

// ---------------------------------------------------------------------------
// x [B,414,S] fp32 -> xpad [S][B][416] fp16 (cols 414,415 zero), LDS-tiled
// so both global read (over s) and write (over i) are coalesced.
// ---------------------------------------------------------------------------
__global__ __launch_bounds__(256) void transpose_pad_x_fp16(
    const float* __restrict__ x, f16* __restrict__ xp)
{
    __shared__ float T[64][130];
    const int tid = threadIdx.x;
    const int b  = blockIdx.x;
    const int i0 = blockIdx.y * 64;
#pragma unroll
    for (int it = 0; it < 32; ++it) {
        int idx = it * 256 + tid;
        int ii = idx >> 7, s = idx & 127;
        int i = i0 + ii;
        T[ii][s] = (i < IN_) ? x[((size_t)b * IN_ + i) * SS + s] : 0.f;
    }
    __syncthreads();
#pragma unroll
    for (int it = 0; it < 32; ++it) {
        int idx = it * 256 + tid;
        int ii = idx & 63, s = idx >> 6;
        int i = i0 + ii;
        if (i < INP) xp[((size_t)s * BB + b) * INP + i] = (f16)T[ii][s];
    }
}

// ---------------------------------------------------------------------------
// One GEMM phase per wave: weights (LDS, M-operand) x activations (global,
// N-operand). Wave tile: 16 weight-cols x 32 batches (2 MFMA acc chains).
// Swizzled LDS: element (c,k) at (c<<10) + (k&7) + ((k&~7) ^ ((c&7)<<3)).
// ---------------------------------------------------------------------------
template<int NCH>
__device__ __forceinline__ void mfma_phase(
    const f16* __restrict__ A, int Ks,      // activation rows (batch-major)
    const f16* __restrict__ Wl, int swz,    // LDS row base (c_row<<10), swizzle
    int ldsBase, int lane,
    float4_& acc0, float4_& acc1)
{
    const int q8 = 8 * (lane >> 4);
    const f16* Ap  = A + (size_t)(lane & 15) * Ks + q8;
    const f16* Ap2 = Ap + 16 * (size_t)Ks;
    int koff = ldsBase + q8;

    half8 wf = *(const half8*)(Wl + (koff ^ swz));
    half8 a0 = *(const half8*)(Ap);
    half8 a1 = *(const half8*)(Ap2);
#pragma unroll
    for (int kt = 0; kt < NCH - 1; ++kt) {
        half8 wn  = *(const half8*)(Wl + ((koff + 32) ^ swz));
        half8 a0n = *(const half8*)(Ap + 32);
        half8 a1n = *(const half8*)(Ap2 + 32);
        acc0 = __builtin_amdgcn_mfma_f32_16x16x32_f16(wf, a0, acc0, 0, 0, 0);
        acc1 = __builtin_amdgcn_mfma_f32_16x16x32_f16(wf, a1, acc1, 0, 0, 0);
        wf = wn; a0 = a0n; a1 = a1n;
        koff += 32; Ap += 32; Ap2 += 32;
    }
    acc0 = __builtin_amdgcn_mfma_f32_16x16x32_f16(wf, a0, acc0, 0, 0, 0);
    acc1 = __builtin_amdgcn_mfma_f32_16x16x32_f16(wf, a1, acc1, 0, 0, 0);
}

// ---------------------------------------------------------------------------
// Persistent cooperative kernel. 512 WGs x 256 thr (2 WGs/CU, 8 waves/CU).
// WGs 0..255: layer 0; 256..511: layer 1 (lags one step).
// Per WG: 64 batches x 8 jj (x 4 gates) = 64 x 32 gate-cols.
// Weight tile (32 cols x 1024 k fp16 = 64 KB) resident in LDS all steps.
// Gate-col order c = 4*jj_local + gate => each lane's 4 acc regs are the
// i,f,g,o preacts of one (batch, jj): epilogue is lane-local; c in regs.
// ---------------------------------------------------------------------------
__global__ __launch_bounds__(256, 2) void lstm_persist_mfma(
    const f16* __restrict__ xpad,     // [S][B][416]
    const float* __restrict__ wih0,   // [2048][414]
    const float* __restrict__ whh0,   // [2048][512]
    const float* __restrict__ bih0, const float* __restrict__ bhh0,
    const float* __restrict__ wih1,   // [2048][512]
    const float* __restrict__ whh1,   // [2048][512]
    const float* __restrict__ bih1, const float* __restrict__ bhh1,
    f16* __restrict__ h1ring,         // [2][B][512]
    f16* __restrict__ h2)             // [S][B][512]
{
    cg::grid_group grid = cg::this_grid();
    __shared__ f16 Wlds[32 * 1024];   // exactly 64 KB

    const int tid  = threadIdx.x;
    const int lane = tid & 63;
    const int w    = tid >> 6;        // wave 0..3
    const int wg   = blockIdx.x;
    const int layer = wg >> 8;
    const int r    = wg & 255;
    const int bb   = (r >> 6) * 64;   // batch block (4 of 64)
    const int jj0  = (r & 63) * 8;    // jj block (64 of 8)

    // ---- stage weights (one-time): LDS col c <-> weight row j ----
    for (int idx = tid; idx < 32 * 1024; idx += 256) {
        int c = idx >> 10, k = idx & 1023;
        int j = (c & 3) * HH + jj0 + (c >> 2);
        float v;
        if (layer == 0) {
            if (k < IN_)                      v = wih0[(size_t)j * IN_ + k];
            else if (k >= INP && k < INP+HH)  v = whh0[(size_t)j * HH + (k - INP)];
            else                              v = 0.f;
        } else {
            v = (k < HH) ? wih1[(size_t)j * HH + k]
                         : whh1[(size_t)j * HH + (k - HH)];
        }
        int sk = (k & 7) | ((k & ~7) ^ ((c & 7) << 3));
        Wlds[(c << 10) + sk] = (f16)v;
    }
    __syncthreads();

    const int c_row = (lane & 15) + 16 * (w & 1);
    const int swz   = (c_row & 7) << 3;
    const f16* Wl   = &Wlds[c_row << 10];
    const int nb    = bb + 32 * (w >> 1);            // wave's 32-batch base
    const int jj    = jj0 + 4 * (w & 1) + (lane >> 4);
    const int b0    = nb + (lane & 15);

    const float* bi_p = layer ? bih1 : bih0;
    const float* bh_p = layer ? bhh1 : bhh0;
    float bs[4];
#pragma unroll
    for (int g = 0; g < 4; ++g) bs[g] = bi_p[g * HH + jj] + bh_p[g * HH + jj];

    float c0 = 0.f, c1 = 0.f;

    for (int t = 0; t <= SS; ++t) {
        const bool active = layer ? (t >= 1) : (t < SS);
        if (active) {
            const int s = layer ? (t - 1) : t;
            float4_ acc0 = {0.f, 0.f, 0.f, 0.f};
            float4_ acc1 = {0.f, 0.f, 0.f, 0.f};
            const f16* hp = h1ring + (size_t)((t - 1) & 1) * BB * HH;

            if (layer == 0) {
                mfma_phase<13>(xpad + (size_t)t * BB * INP + (size_t)nb * INP,
                               INP, Wl, swz, 0, lane, acc0, acc1);
                if (t >= 1)
                    mfma_phase<16>(hp + (size_t)nb * HH, HH, Wl, swz, INP,
                                   lane, acc0, acc1);
            } else {
                mfma_phase<16>(hp + (size_t)nb * HH, HH, Wl, swz, 0,
                               lane, acc0, acc1);
                if (s >= 1)
                    mfma_phase<16>(h2 + (size_t)(s - 1) * BB * HH + (size_t)nb * HH,
                                   HH, Wl, swz, HH, lane, acc0, acc1);
            }

            f16* hout = layer ? (h2 + (size_t)s * BB * HH)
                              : (h1ring + (size_t)(t & 1) * BB * HH);
            {
                float xi = acc0[0] + bs[0], xf = acc0[1] + bs[1];
                float xg = acc0[2] + bs[2], xo = acc0[3] + bs[3];
                float ig = 1.f / (1.f + __expf(-xi));
                float fg = 1.f / (1.f + __expf(-xf));
                float gg = tanhf(xg);
                float og = 1.f / (1.f + __expf(-xo));
                c0 = fg * c0 + ig * gg;
                hout[(size_t)b0 * HH + jj] = (f16)(og * tanhf(c0));
            }
            {
                float xi = acc1[0] + bs[0], xf = acc1[1] + bs[1];
                float xg = acc1[2] + bs[2], xo = acc1[3] + bs[3];
                float ig = 1.f / (1.f + __expf(-xi));
                float fg = 1.f / (1.f + __expf(-xf));
                float gg = tanhf(xg);
                float og = 1.f / (1.f + __expf(-xo));
                c1 = fg * c1 + ig * gg;
                hout[(size_t)(b0 + 16) * HH + jj] = (f16)(og * tanhf(c1));
            }
        }
        grid.sync();
    }
}

// ---------------------------------------------------------------------------
// FC: out[b, oc, n, s] = fc_b[o] + h2[(s*B+b), :] @ fc_w[o, :]  (h2 fp16)
// ---------------------------------------------------------------------------
__global__ __launch_bounds__(256) void fc_kernel(
    const f16* __restrict__ h2,       // [S*B, 512] fp16
    const float* __restrict__ fc_w,   // [414, 512]
    const float* __restrict__ fc_b,   // [414]
    float* __restrict__ out)          // [B, 2, 207, 128]
{
    __shared__ float As2[32][33];
    __shared__ float Bs2[64][33];

    const int tid = threadIdx.x;
    const int ot  = tid & 15;
    const int bp  = tid >> 4;
    const int mb  = blockIdx.x * 32;
    const int o0  = blockIdx.y * 64;

    float acc[2][4];
#pragma unroll
    for (int u = 0; u < 2; ++u)
#pragma unroll
        for (int v = 0; v < 4; ++v) acc[u][v] = 0.f;

    for (int k0 = 0; k0 < HH; k0 += 32) {
        __syncthreads();
#pragma unroll
        for (int u = 0; u < 4; ++u) {
            int idx = u * 256 + tid;
            int ml = idx >> 5, kk = idx & 31;
            As2[ml][kk] = (float)h2[(size_t)(mb + ml) * HH + k0 + kk];
        }
#pragma unroll
        for (int u = 0; u < 8; ++u) {
            int idx = u * 256 + tid;
            int rr = idx >> 5, kk = idx & 31;
            int o = o0 + rr;
            Bs2[rr][kk] = (o < OUT_) ? fc_w[(size_t)o * HH + k0 + kk] : 0.f;
        }
        __syncthreads();
#pragma unroll
        for (int kk = 0; kk < 32; ++kk) {
            float a0 = As2[bp * 2][kk];
            float a1 = As2[bp * 2 + 1][kk];
            float w0 = Bs2[ot][kk];
            float w1 = Bs2[16 + ot][kk];
            float w2 = Bs2[32 + ot][kk];
            float w3 = Bs2[48 + ot][kk];
            acc[0][0] += a0 * w0;  acc[0][1] += a0 * w1;
            acc[0][2] += a0 * w2;  acc[0][3] += a0 * w3;
            acc[1][0] += a1 * w0;  acc[1][1] += a1 * w1;
            acc[1][2] += a1 * w2;  acc[1][3] += a1 * w3;
        }
    }

#pragma unroll
    for (int u = 0; u < 2; ++u) {
        const int m = mb + bp * 2 + u;
        const int s = m >> 8;
        const int b = m & 255;
#pragma unroll
        for (int v = 0; v < 4; ++v) {
            const int o = o0 + v * 16 + ot;
            if (o < OUT_) {
                const int oc = (o < NN) ? 0 : 1;
                const int n  = (o < NN) ? o : o - NN;
                out[(((size_t)b * 2 + oc) * NN + n) * SS + s] = acc[u][v] + fc_b[o];
            }
        }
    }
}

// ---------------------------------------------------------------------------
extern "C" void kernel_launch(void* const* d_in, const int* in_sizes, int n_in,
                              void* d_out, int out_size, void* d_ws, size_t ws_size,
                              hipStream_t stream)
{
    const float* x     = (const float*)d_in[0];
    const float* w_ih0 = (const float*)d_in[1];
    const float* w_hh0 = (const float*)d_in[2];
    const float* b_ih0 = (const float*)d_in[3];
    const float* b_hh0 = (const float*)d_in[4];
    const float* w_ih1 = (const float*)d_in[5];
    const float* w_hh1 = (const float*)d_in[6];
    const float* b_ih1 = (const float*)d_in[7];
    const float* b_hh1 = (const float*)d_in[8];
    const float* fc_w  = (const float*)d_in[9];
    const float* fc_b  = (const float*)d_in[10];
    float* out = (float*)d_out;

    char* ws = (char*)d_ws;
    f16* xpad   = (f16*)ws;                                  // S*B*416 halves
    f16* h1ring = (f16*)(ws + (size_t)SS * BB * INP * 2);    // 2*B*512
    f16* h2     = (f16*)(ws + (size_t)SS * BB * INP * 2
                            + (size_t)2 * BB * HH * 2);      // S*B*512

    // 1) transpose + pad + fp16-cast x
    transpose_pad_x_fp16<<<dim3(BB, 7), 256, 0, stream>>>(x, xpad);

    // 2) persistent MFMA LSTM (both layers pipelined, 129 grid syncs)
    {
        void* args[] = {
            (void*)&xpad, (void*)&w_ih0, (void*)&w_hh0,
            (void*)&b_ih0, (void*)&b_hh0,
            (void*)&w_ih1, (void*)&w_hh1, (void*)&b_ih1, (void*)&b_hh1,
            (void*)&h1ring, (void*)&h2
        };
        hipLaunchCooperativeKernel((void*)lstm_persist_mfma,
                                   dim3(512), dim3(256), args, 0, stream);
    }

    // 3) FC + output transpose
    fc_kernel<<<dim3(SS * BB / 32, (OUT_ + 63) / 64), 256, 0, stream>>>(
        h2, fc_w, fc_b, out);
}

// Round 4
// 3865.731 us; speedup vs baseline: 6.6197x; 2.5394x over previous
//
#include <hip/hip_runtime.h>
#include <hip/hip_bf16.h>

typedef _Float16 f16;
typedef _Float16 half8 __attribute__((ext_vector_type(8)));
typedef float float4_ __attribute__((ext_vector_type(4)));

#define BB   256
#define SS   128
#define HH   512
#define IN_  414
#define INP  416
#define NN   207
#define OUT_ 414

// flags: [layer(2)][bb4(4)][s(128)] with 32-int stride (128B, no false sharing)
#define FLAG_STRIDE 32
#define FLAG_BYTES  (2 * 4 * SS * FLAG_STRIDE * 4)

// ---------------------------------------------------------------------------
// x [B,414,S] fp32 -> xpad [S][B][416] fp16 (cols 414,415 zero), LDS-tiled.
// ---------------------------------------------------------------------------
__global__ __launch_bounds__(256) void transpose_pad_x_fp16(
    const float* __restrict__ x, f16* __restrict__ xp)
{
    __shared__ float T[64][130];
    const int tid = threadIdx.x;
    const int b  = blockIdx.x;
    const int i0 = blockIdx.y * 64;
#pragma unroll
    for (int it = 0; it < 32; ++it) {
        int idx = it * 256 + tid;
        int ii = idx >> 7, s = idx & 127;
        int i = i0 + ii;
        T[ii][s] = (i < IN_) ? x[((size_t)b * IN_ + i) * SS + s] : 0.f;
    }
    __syncthreads();
#pragma unroll
    for (int it = 0; it < 32; ++it) {
        int idx = it * 256 + tid;
        int ii = idx & 63, s = idx >> 6;
        int i = i0 + ii;
        if (i < INP) xp[((size_t)s * BB + b) * INP + i] = (f16)T[ii][s];
    }
}

// ---------------------------------------------------------------------------
// Flag sync helpers (device-scope producer/consumer, per 64-WG group)
// ---------------------------------------------------------------------------
__device__ __forceinline__ void wait_flag(int* f, int target)
{
    if (threadIdx.x == 0) {
        while (__hip_atomic_load(f, __ATOMIC_RELAXED, __HIP_MEMORY_SCOPE_AGENT) < target)
            __builtin_amdgcn_s_sleep(2);
        __builtin_amdgcn_fence(__ATOMIC_ACQUIRE, "agent");   // inv L1/L2
    }
    __syncthreads();
}

__device__ __forceinline__ void signal_flag(int* f)
{
    __syncthreads();   // all WG threads' stores drained (vmcnt 0 before barrier)
    if (threadIdx.x == 0) {
        __builtin_amdgcn_fence(__ATOMIC_RELEASE, "agent");   // wb L2
        __hip_atomic_fetch_add(f, 1, __ATOMIC_RELAXED, __HIP_MEMORY_SCOPE_AGENT);
    }
}

// ---------------------------------------------------------------------------
// MFMA phase: weights (LDS, A/M-operand) x activations (global, B/N-operand).
// Wave tile: 16 weight-cols x 32 activation rows (2 acc chains).
// Ks = activation row stride (halves); NCH = number of 32-k chunks.
// LDS swizzle: element (c,k) at colbase + (k&7) + ((k&~7) ^ ((c&7)<<3)).
// ---------------------------------------------------------------------------
template<int NCH>
__device__ __forceinline__ void mfma_phase(
    const f16* __restrict__ A, int Ks,
    const f16* __restrict__ Wl, int swz,
    int ldsBase, int lane,
    float4_& acc0, float4_& acc1)
{
    const int q8 = 8 * (lane >> 4);
    const f16* Ap  = A + (size_t)(lane & 15) * Ks + q8;
    const f16* Ap2 = Ap + 16 * (size_t)Ks;
    int koff = ldsBase + q8;

    half8 wf = *(const half8*)(Wl + (koff ^ swz));
    half8 a0 = *(const half8*)(Ap);
    half8 a1 = *(const half8*)(Ap2);
#pragma unroll
    for (int kt = 0; kt < NCH - 1; ++kt) {
        half8 wn  = *(const half8*)(Wl + ((koff + 32) ^ swz));
        half8 a0n = *(const half8*)(Ap + 32);
        half8 a1n = *(const half8*)(Ap2 + 32);
        acc0 = __builtin_amdgcn_mfma_f32_16x16x32_f16(wf, a0, acc0, 0, 0, 0);
        acc1 = __builtin_amdgcn_mfma_f32_16x16x32_f16(wf, a1, acc1, 0, 0, 0);
        wf = wn; a0 = a0n; a1 = a1n;
        koff += 32; Ap += 32; Ap2 += 32;
    }
    acc0 = __builtin_amdgcn_mfma_f32_16x16x32_f16(wf, a0, acc0, 0, 0, 0);
    acc1 = __builtin_amdgcn_mfma_f32_16x16x32_f16(wf, a1, acc1, 0, 0, 0);
}

// ---------------------------------------------------------------------------
// Persistent LSTM, flag-synced. 512 WGs x 256 thr (2 WGs/CU).
// WGs 0..255: layer 0; 256..511: layer 1. Per WG: 64 batches x 8 jj x 4 gates.
// Weight tile (32 cols x 1024 k fp16 = 64 KB) resident in LDS all steps.
// Gate-col order c = 4*jj_local + gate => lane-local epilogue; c-state in regs.
// ---------------------------------------------------------------------------
__global__ __launch_bounds__(256, 2) void lstm_persist_mfma(
    const f16* __restrict__ xpad,     // [S][B][416]
    const float* __restrict__ wih0,   // [2048][414]
    const float* __restrict__ whh0,   // [2048][512]
    const float* __restrict__ bih0, const float* __restrict__ bhh0,
    const float* __restrict__ wih1,   // [2048][512]
    const float* __restrict__ whh1,   // [2048][512]
    const float* __restrict__ bih1, const float* __restrict__ bhh1,
    f16* __restrict__ h1,             // [S][B][512]
    f16* __restrict__ h2,             // [S][B][512]
    int* __restrict__ flags)
{
    __shared__ f16 Wlds[32 * 1024];   // 64 KB

    const int tid  = threadIdx.x;
    const int lane = tid & 63;
    const int w    = tid >> 6;
    const int wg   = blockIdx.x;
    const int layer = wg >> 8;
    const int r    = wg & 255;
    const int bb   = (r >> 6) * 64;
    const int bb4  = r >> 6;
    const int jj0  = (r & 63) * 8;

    // ---- stage weights (once): LDS col c <-> weight row j = (c&3)*H + jj0 + (c>>2)
    for (int idx = tid; idx < 32 * 1024; idx += 256) {
        int c = idx >> 10, k = idx & 1023;
        int j = (c & 3) * HH + jj0 + (c >> 2);
        float v;
        if (layer == 0) {
            if (k < IN_)                       v = wih0[(size_t)j * IN_ + k];
            else if (k >= INP && k < INP + HH) v = whh0[(size_t)j * HH + (k - INP)];
            else                               v = 0.f;
        } else {
            v = (k < HH) ? wih1[(size_t)j * HH + k]
                         : whh1[(size_t)j * HH + (k - HH)];
        }
        int sk = (k & 7) | ((k & ~7) ^ ((c & 7) << 3));
        Wlds[(c << 10) + sk] = (f16)v;
    }
    __syncthreads();

    const int c_row = (lane & 15) + 16 * (w & 1);
    const int swz   = (c_row & 7) << 3;
    const f16* Wl   = &Wlds[c_row << 10];
    const int nb    = bb + 32 * (w >> 1);
    const int jj    = jj0 + 4 * (w & 1) + (lane >> 4);
    const int b0    = nb + (lane & 15);

    const float* bi_p = layer ? bih1 : bih0;
    const float* bh_p = layer ? bhh1 : bhh0;
    float bs[4];
#pragma unroll
    for (int g = 0; g < 4; ++g) bs[g] = bi_p[g * HH + jj] + bh_p[g * HH + jj];

    int* flag0 = flags + (size_t)bb4 * SS * FLAG_STRIDE;
    int* flag1 = flags + (size_t)(4 + bb4) * SS * FLAG_STRIDE;

    float c0 = 0.f, c1 = 0.f;

    for (int s = 0; s < SS; ++s) {
        float4_ acc0 = {0.f, 0.f, 0.f, 0.f};
        float4_ acc1 = {0.f, 0.f, 0.f, 0.f};

        if (layer == 0) {
            // x-projection first: no dependency, overlaps others' step s-1
            mfma_phase<13>(xpad + (size_t)s * BB * INP + (size_t)nb * INP,
                           INP, Wl, swz, 0, lane, acc0, acc1);
            if (s >= 1) {
                wait_flag(flag0 + (s - 1) * FLAG_STRIDE, 64);
                mfma_phase<16>(h1 + (size_t)(s - 1) * BB * HH + (size_t)nb * HH,
                               HH, Wl, swz, INP, lane, acc0, acc1);
            }
        } else {
            wait_flag(flag0 + s * FLAG_STRIDE, 64);
            mfma_phase<16>(h1 + (size_t)s * BB * HH + (size_t)nb * HH,
                           HH, Wl, swz, 0, lane, acc0, acc1);
            if (s >= 1) {
                wait_flag(flag1 + (s - 1) * FLAG_STRIDE, 64);
                mfma_phase<16>(h2 + (size_t)(s - 1) * BB * HH + (size_t)nb * HH,
                               HH, Wl, swz, HH, lane, acc0, acc1);
            }
        }

        f16* hout = (layer ? h2 : h1) + (size_t)s * BB * HH;
        {
            float xi = acc0[0] + bs[0], xf = acc0[1] + bs[1];
            float xg = acc0[2] + bs[2], xo = acc0[3] + bs[3];
            float ig = 1.f / (1.f + __expf(-xi));
            float fg = 1.f / (1.f + __expf(-xf));
            float gg = tanhf(xg);
            float og = 1.f / (1.f + __expf(-xo));
            c0 = fg * c0 + ig * gg;
            hout[(size_t)b0 * HH + jj] = (f16)(og * tanhf(c0));
        }
        {
            float xi = acc1[0] + bs[0], xf = acc1[1] + bs[1];
            float xg = acc1[2] + bs[2], xo = acc1[3] + bs[3];
            float ig = 1.f / (1.f + __expf(-xi));
            float fg = 1.f / (1.f + __expf(-xf));
            float gg = tanhf(xg);
            float og = 1.f / (1.f + __expf(-xo));
            c1 = fg * c1 + ig * gg;
            hout[(size_t)(b0 + 16) * HH + jj] = (f16)(og * tanhf(c1));
        }

        signal_flag((layer ? flag1 : flag0) + s * FLAG_STRIDE);
    }
}

// ---------------------------------------------------------------------------
// FC via MFMA, same weights-in-LDS structure. Grid (256 b, 7 o-blocks).
// WG: 64 o-cols x 512 k fp16 in LDS (64 KB); wave w owns o-cols 16w..16w+15.
// Loop si=0..3: wave tile 16 o x 32 s (acc0: s0..s0+15, acc1: +16).
// out[b, oc, n, s]: lanes 0..15 write consecutive s -> coalesced.
// ---------------------------------------------------------------------------
__global__ __launch_bounds__(256, 2) void fc_mfma(
    const f16* __restrict__ h2,       // [S*B][512], row m = s*256 + b
    const float* __restrict__ fc_w,   // [414][512]
    const float* __restrict__ fc_b,   // [414]
    float* __restrict__ out)          // [B, 2, 207, 128]
{
    __shared__ f16 W[64 * 512];       // 64 KB

    const int tid = threadIdx.x;
    const int b   = blockIdx.x;
    const int o0  = blockIdx.y * 64;

    for (int idx = tid; idx < 64 * 512; idx += 256) {
        int c = idx >> 9, k = idx & 511;
        int o = o0 + c;
        float v = (o < OUT_) ? fc_w[(size_t)o * HH + k] : 0.f;
        int sk = (k & 7) | ((k & ~7) ^ ((c & 7) << 3));
        W[(c << 9) + sk] = (f16)v;
    }
    __syncthreads();

    const int lane  = tid & 63;
    const int w     = tid >> 6;
    const int c_row = (lane & 15) + 16 * w;
    const int swz   = (c_row & 7) << 3;
    const f16* Wl   = &W[c_row << 9];
    const int RS    = BB * HH;        // h2 row stride between consecutive s

    for (int si = 0; si < 4; ++si) {
        const int s0 = si * 32;
        float4_ acc0 = {0.f, 0.f, 0.f, 0.f};
        float4_ acc1 = {0.f, 0.f, 0.f, 0.f};
        // activation rows: fixed b, s = s0 + (lane&15) (+16 for acc1)
        mfma_phase<16>(h2 + (size_t)s0 * RS + (size_t)b * HH,
                       RS, Wl, swz, 0, lane, acc0, acc1);

#pragma unroll
        for (int reg = 0; reg < 4; ++reg) {
            const int o = o0 + 16 * w + (lane >> 4) * 4 + reg;
            if (o < OUT_) {
                const int oc = (o < NN) ? 0 : 1;
                const int n  = (o < NN) ? o : o - NN;
                float* op = out + (((size_t)b * 2 + oc) * NN + n) * SS;
                op[s0 + (lane & 15)]      = acc0[reg] + fc_b[o];
                op[s0 + 16 + (lane & 15)] = acc1[reg] + fc_b[o];
            }
        }
    }
}

// ---------------------------------------------------------------------------
extern "C" void kernel_launch(void* const* d_in, const int* in_sizes, int n_in,
                              void* d_out, int out_size, void* d_ws, size_t ws_size,
                              hipStream_t stream)
{
    const float* x     = (const float*)d_in[0];
    const float* w_ih0 = (const float*)d_in[1];
    const float* w_hh0 = (const float*)d_in[2];
    const float* b_ih0 = (const float*)d_in[3];
    const float* b_hh0 = (const float*)d_in[4];
    const float* w_ih1 = (const float*)d_in[5];
    const float* w_hh1 = (const float*)d_in[6];
    const float* b_ih1 = (const float*)d_in[7];
    const float* b_hh1 = (const float*)d_in[8];
    const float* fc_w  = (const float*)d_in[9];
    const float* fc_b  = (const float*)d_in[10];
    float* out = (float*)d_out;

    char* ws = (char*)d_ws;
    int* flags = (int*)ws;
    f16* xpad  = (f16*)(ws + FLAG_BYTES);
    f16* h1    = (f16*)(ws + FLAG_BYTES + (size_t)SS * BB * INP * 2);
    f16* h2    = (f16*)(ws + FLAG_BYTES + (size_t)SS * BB * INP * 2
                           + (size_t)SS * BB * HH * 2);

    // 0) zero the sync flags (ws is poisoned 0xAA before every launch)
    hipMemsetAsync(flags, 0, FLAG_BYTES, stream);

    // 1) transpose + pad + fp16-cast x
    transpose_pad_x_fp16<<<dim3(BB, 7), 256, 0, stream>>>(x, xpad);

    // 2) persistent MFMA LSTM, flag-synced (cooperative only for co-residency)
    {
        void* args[] = {
            (void*)&xpad, (void*)&w_ih0, (void*)&w_hh0,
            (void*)&b_ih0, (void*)&b_hh0,
            (void*)&w_ih1, (void*)&w_hh1, (void*)&b_ih1, (void*)&b_hh1,
            (void*)&h1, (void*)&h2, (void*)&flags
        };
        hipLaunchCooperativeKernel((void*)lstm_persist_mfma,
                                   dim3(512), dim3(256), args, 0, stream);
    }

    // 3) FC via MFMA + output transpose
    fc_mfma<<<dim3(BB, 7), 256, 0, stream>>>(h2, fc_w, fc_b, out);
}

// Round 5
// 3612.633 us; speedup vs baseline: 7.0834x; 1.0701x over previous
//
#include <hip/hip_runtime.h>
#include <hip/hip_bf16.h>

typedef _Float16 f16;
typedef _Float16 half8 __attribute__((ext_vector_type(8)));
typedef float float4_ __attribute__((ext_vector_type(4)));

#define BB   256
#define SS   128
#define HH   512
#define IN_  414
#define INP  416
#define NN   207
#define OUT_ 414

// flags: [layer(2)][bb4(4)][s(128)] with 32-int stride (128B lines)
#define FLAG_STRIDE 32
#define FLAG_BYTES  (2 * 4 * SS * FLAG_STRIDE * 4)

// ---------------------------------------------------------------------------
// x [B,414,S] fp32 -> xpad [S][B][416] fp16 (cols 414,415 zero), LDS-tiled.
// ---------------------------------------------------------------------------
__global__ __launch_bounds__(256) void transpose_pad_x_fp16(
    const float* __restrict__ x, f16* __restrict__ xp)
{
    __shared__ float T[64][130];
    const int tid = threadIdx.x;
    const int b  = blockIdx.x;
    const int i0 = blockIdx.y * 64;
#pragma unroll
    for (int it = 0; it < 32; ++it) {
        int idx = it * 256 + tid;
        int ii = idx >> 7, s = idx & 127;
        int i = i0 + ii;
        T[ii][s] = (i < IN_) ? x[((size_t)b * IN_ + i) * SS + s] : 0.f;
    }
    __syncthreads();
#pragma unroll
    for (int it = 0; it < 32; ++it) {
        int idx = it * 256 + tid;
        int ii = idx & 63, s = idx >> 6;
        int i = i0 + ii;
        if (i < INP) xp[((size_t)s * BB + b) * INP + i] = (f16)T[ii][s];
    }
}

// ---------------------------------------------------------------------------
// Flag sync helpers (device-scope producer/consumer, per 64-WG group)
// ---------------------------------------------------------------------------
__device__ __forceinline__ void wait_one(int* f)
{
    if (threadIdx.x == 0) {
        while (__hip_atomic_load(f, __ATOMIC_RELAXED, __HIP_MEMORY_SCOPE_AGENT) < 64)
            __builtin_amdgcn_s_sleep(1);
        __builtin_amdgcn_fence(__ATOMIC_ACQUIRE, "agent");   // inv stale L1/L2
    }
    __syncthreads();
}

__device__ __forceinline__ void wait_two(int* fA, int* fB)
{
    if (threadIdx.x == 0) {
        while (__hip_atomic_load(fA, __ATOMIC_RELAXED, __HIP_MEMORY_SCOPE_AGENT) < 64)
            __builtin_amdgcn_s_sleep(1);
        while (__hip_atomic_load(fB, __ATOMIC_RELAXED, __HIP_MEMORY_SCOPE_AGENT) < 64)
            __builtin_amdgcn_s_sleep(1);
        __builtin_amdgcn_fence(__ATOMIC_ACQUIRE, "agent");   // one inv for both
    }
    __syncthreads();
}

__device__ __forceinline__ void signal_flag(int* f)
{
    __syncthreads();   // all WG stores drained (vmcnt 0 before s_barrier)
    if (threadIdx.x == 0) {
        // h stores are write-through atomics -> L2 has ~no dirty lines,
        // so this release (wbl2) is near-free but keeps the model sound.
        __builtin_amdgcn_fence(__ATOMIC_RELEASE, "agent");
        __hip_atomic_fetch_add(f, 1, __ATOMIC_RELAXED, __HIP_MEMORY_SCOPE_AGENT);
    }
}

// write-through fp16 store (agent-scope relaxed atomic, bypasses dirty-L2)
__device__ __forceinline__ void store_h(f16* p, float v)
{
    f16 hv = (f16)v;
    unsigned short us;
    __builtin_memcpy(&us, &hv, 2);
    __hip_atomic_store((unsigned short*)p, us,
                       __ATOMIC_RELAXED, __HIP_MEMORY_SCOPE_AGENT);
}

// ---------------------------------------------------------------------------
// MFMA phase: weights (LDS, A/M-operand) x activations (global, B/N-operand).
// Wave tile: 16 weight-cols x 32 activation rows (2 acc chains).
// DEEP PRELOAD: all NCH chunks' A-fragments loaded before the MFMA chain ->
// one memory round-trip instead of NCH sequential ones.
// LDS swizzle: element (c,k) at colbase + (k&7) + ((k&~7) ^ ((c&7)<<3)).
// ---------------------------------------------------------------------------
template<int NCH>
__device__ __forceinline__ void mfma_phase(
    const f16* __restrict__ A, int Ks,
    const f16* __restrict__ Wl, int swz,
    int ldsBase, int lane,
    float4_& acc0, float4_& acc1)
{
    const int q8 = 8 * (lane >> 4);
    const f16* Ap  = A + (size_t)(lane & 15) * Ks + q8;
    const f16* Ap2 = Ap + 16 * (size_t)Ks;

    half8 a0[NCH], a1[NCH];
#pragma unroll
    for (int kt = 0; kt < NCH; ++kt) {
        a0[kt] = *(const half8*)(Ap  + 32 * kt);
        a1[kt] = *(const half8*)(Ap2 + 32 * kt);
    }

    const int koff = ldsBase + q8;
#pragma unroll
    for (int kt = 0; kt < NCH; ++kt) {
        half8 wf = *(const half8*)(Wl + ((koff + 32 * kt) ^ swz));
        acc0 = __builtin_amdgcn_mfma_f32_16x16x32_f16(wf, a0[kt], acc0, 0, 0, 0);
        acc1 = __builtin_amdgcn_mfma_f32_16x16x32_f16(wf, a1[kt], acc1, 0, 0, 0);
    }
}

// ---------------------------------------------------------------------------
// Persistent LSTM, flag-synced. 512 WGs x 256 thr (2 WGs/CU).
// WGs 0..255: layer 0; 256..511: layer 1. Per WG: 64 batches x 8 jj x 4 gates.
// Weight tile (32 cols x 1024 k fp16 = 64 KB) resident in LDS all steps.
// Gate-col order c = 4*jj_local + gate => lane-local epilogue; c-state in regs.
// ---------------------------------------------------------------------------
__global__ __launch_bounds__(256, 2) void lstm_persist_mfma(
    const f16* __restrict__ xpad,     // [S][B][416]
    const float* __restrict__ wih0,   // [2048][414]
    const float* __restrict__ whh0,   // [2048][512]
    const float* __restrict__ bih0, const float* __restrict__ bhh0,
    const float* __restrict__ wih1,   // [2048][512]
    const float* __restrict__ whh1,   // [2048][512]
    const float* __restrict__ bih1, const float* __restrict__ bhh1,
    f16* __restrict__ h1,             // [S][B][512]
    f16* __restrict__ h2,             // [S][B][512]
    int* __restrict__ flags)
{
    __shared__ f16 Wlds[32 * 1024];   // 64 KB

    const int tid  = threadIdx.x;
    const int lane = tid & 63;
    const int w    = tid >> 6;
    const int wg   = blockIdx.x;
    const int layer = wg >> 8;
    const int r    = wg & 255;
    const int bb   = (r >> 6) * 64;
    const int bb4  = r >> 6;
    const int jj0  = (r & 63) * 8;

    // ---- stage weights (once): LDS col c <-> weight row j = (c&3)*H + jj0 + (c>>2)
    for (int idx = tid; idx < 32 * 1024; idx += 256) {
        int c = idx >> 10, k = idx & 1023;
        int j = (c & 3) * HH + jj0 + (c >> 2);
        float v;
        if (layer == 0) {
            if (k < IN_)                       v = wih0[(size_t)j * IN_ + k];
            else if (k >= INP && k < INP + HH) v = whh0[(size_t)j * HH + (k - INP)];
            else                               v = 0.f;
        } else {
            v = (k < HH) ? wih1[(size_t)j * HH + k]
                         : whh1[(size_t)j * HH + (k - HH)];
        }
        int sk = (k & 7) | ((k & ~7) ^ ((c & 7) << 3));
        Wlds[(c << 10) + sk] = (f16)v;
    }
    __syncthreads();

    const int c_row = (lane & 15) + 16 * (w & 1);
    const int swz   = (c_row & 7) << 3;
    const f16* Wl   = &Wlds[c_row << 10];
    const int nb    = bb + 32 * (w >> 1);
    const int jj    = jj0 + 4 * (w & 1) + (lane >> 4);
    const int b0    = nb + (lane & 15);

    const float* bi_p = layer ? bih1 : bih0;
    const float* bh_p = layer ? bhh1 : bhh0;
    float bs[4];
#pragma unroll
    for (int g = 0; g < 4; ++g) bs[g] = bi_p[g * HH + jj] + bh_p[g * HH + jj];

    int* flag0 = flags + (size_t)bb4 * SS * FLAG_STRIDE;
    int* flag1 = flags + (size_t)(4 + bb4) * SS * FLAG_STRIDE;

    float c0 = 0.f, c1 = 0.f;

    for (int s = 0; s < SS; ++s) {
        float4_ acc0 = {0.f, 0.f, 0.f, 0.f};
        float4_ acc1 = {0.f, 0.f, 0.f, 0.f};

        if (layer == 0) {
            // x-projection first: no dependency, overlaps the wait
            mfma_phase<13>(xpad + (size_t)s * BB * INP + (size_t)nb * INP,
                           INP, Wl, swz, 0, lane, acc0, acc1);
            if (s >= 1) {
                wait_one(flag0 + (s - 1) * FLAG_STRIDE);
                mfma_phase<16>(h1 + (size_t)(s - 1) * BB * HH + (size_t)nb * HH,
                               HH, Wl, swz, INP, lane, acc0, acc1);
            }
        } else {
            if (s >= 1) wait_two(flag0 + s * FLAG_STRIDE,
                                 flag1 + (s - 1) * FLAG_STRIDE);
            else        wait_one(flag0);
            mfma_phase<16>(h1 + (size_t)s * BB * HH + (size_t)nb * HH,
                           HH, Wl, swz, 0, lane, acc0, acc1);
            if (s >= 1)
                mfma_phase<16>(h2 + (size_t)(s - 1) * BB * HH + (size_t)nb * HH,
                               HH, Wl, swz, HH, lane, acc0, acc1);
        }

        f16* hout = (layer ? h2 : h1) + (size_t)s * BB * HH;
        {
            float xi = acc0[0] + bs[0], xf = acc0[1] + bs[1];
            float xg = acc0[2] + bs[2], xo = acc0[3] + bs[3];
            float ig = 1.f / (1.f + __expf(-xi));
            float fg = 1.f / (1.f + __expf(-xf));
            float gg = tanhf(xg);
            float og = 1.f / (1.f + __expf(-xo));
            c0 = fg * c0 + ig * gg;
            store_h(hout + (size_t)b0 * HH + jj, og * tanhf(c0));
        }
        {
            float xi = acc1[0] + bs[0], xf = acc1[1] + bs[1];
            float xg = acc1[2] + bs[2], xo = acc1[3] + bs[3];
            float ig = 1.f / (1.f + __expf(-xi));
            float fg = 1.f / (1.f + __expf(-xf));
            float gg = tanhf(xg);
            float og = 1.f / (1.f + __expf(-xo));
            c1 = fg * c1 + ig * gg;
            store_h(hout + (size_t)(b0 + 16) * HH + jj, og * tanhf(c1));
        }

        signal_flag((layer ? flag1 : flag0) + s * FLAG_STRIDE);
    }
}

// ---------------------------------------------------------------------------
// FC via MFMA, weights-in-LDS. Grid (256 b, 7 o-blocks).
// WG: 64 o-cols x 512 k fp16 in LDS; wave w owns o-cols 16w..16w+15.
// si=0..3: wave tile 16 o x 32 s. Lanes 0..15 write consecutive s: coalesced.
// ---------------------------------------------------------------------------
__global__ __launch_bounds__(256, 2) void fc_mfma(
    const f16* __restrict__ h2,       // [S*B][512], row m = s*256 + b
    const float* __restrict__ fc_w,   // [414][512]
    const float* __restrict__ fc_b,   // [414]
    float* __restrict__ out)          // [B, 2, 207, 128]
{
    __shared__ f16 W[64 * 512];       // 64 KB

    const int tid = threadIdx.x;
    const int b   = blockIdx.x;
    const int o0  = blockIdx.y * 64;

    for (int idx = tid; idx < 64 * 512; idx += 256) {
        int c = idx >> 9, k = idx & 511;
        int o = o0 + c;
        float v = (o < OUT_) ? fc_w[(size_t)o * HH + k] : 0.f;
        int sk = (k & 7) | ((k & ~7) ^ ((c & 7) << 3));
        W[(c << 9) + sk] = (f16)v;
    }
    __syncthreads();

    const int lane  = tid & 63;
    const int w     = tid >> 6;
    const int c_row = (lane & 15) + 16 * w;
    const int swz   = (c_row & 7) << 3;
    const f16* Wl   = &W[c_row << 9];
    const int RS    = BB * HH;        // h2 row stride between consecutive s

    for (int si = 0; si < 4; ++si) {
        const int s0 = si * 32;
        float4_ acc0 = {0.f, 0.f, 0.f, 0.f};
        float4_ acc1 = {0.f, 0.f, 0.f, 0.f};
        mfma_phase<16>(h2 + (size_t)s0 * RS + (size_t)b * HH,
                       RS, Wl, swz, 0, lane, acc0, acc1);

#pragma unroll
        for (int reg = 0; reg < 4; ++reg) {
            const int o = o0 + 16 * w + (lane >> 4) * 4 + reg;
            if (o < OUT_) {
                const int oc = (o < NN) ? 0 : 1;
                const int n  = (o < NN) ? o : o - NN;
                float* op = out + (((size_t)b * 2 + oc) * NN + n) * SS;
                op[s0 + (lane & 15)]      = acc0[reg] + fc_b[o];
                op[s0 + 16 + (lane & 15)] = acc1[reg] + fc_b[o];
            }
        }
    }
}

// ---------------------------------------------------------------------------
extern "C" void kernel_launch(void* const* d_in, const int* in_sizes, int n_in,
                              void* d_out, int out_size, void* d_ws, size_t ws_size,
                              hipStream_t stream)
{
    const float* x     = (const float*)d_in[0];
    const float* w_ih0 = (const float*)d_in[1];
    const float* w_hh0 = (const float*)d_in[2];
    const float* b_ih0 = (const float*)d_in[3];
    const float* b_hh0 = (const float*)d_in[4];
    const float* w_ih1 = (const float*)d_in[5];
    const float* w_hh1 = (const float*)d_in[6];
    const float* b_ih1 = (const float*)d_in[7];
    const float* b_hh1 = (const float*)d_in[8];
    const float* fc_w  = (const float*)d_in[9];
    const float* fc_b  = (const float*)d_in[10];
    float* out = (float*)d_out;

    char* ws = (char*)d_ws;
    int* flags = (int*)ws;
    f16* xpad  = (f16*)(ws + FLAG_BYTES);
    f16* h1    = (f16*)(ws + FLAG_BYTES + (size_t)SS * BB * INP * 2);
    f16* h2    = (f16*)(ws + FLAG_BYTES + (size_t)SS * BB * INP * 2
                           + (size_t)SS * BB * HH * 2);

    // 0) zero the sync flags
    hipMemsetAsync(flags, 0, FLAG_BYTES, stream);

    // 1) transpose + pad + fp16-cast x
    transpose_pad_x_fp16<<<dim3(BB, 7), 256, 0, stream>>>(x, xpad);

    // 2) persistent MFMA LSTM, flag-synced
    {
        void* args[] = {
            (void*)&xpad, (void*)&w_ih0, (void*)&w_hh0,
            (void*)&b_ih0, (void*)&b_hh0,
            (void*)&w_ih1, (void*)&w_hh1, (void*)&b_ih1, (void*)&b_hh1,
            (void*)&h1, (void*)&h2, (void*)&flags
        };
        hipLaunchCooperativeKernel((void*)lstm_persist_mfma,
                                   dim3(512), dim3(256), args, 0, stream);
    }

    // 3) FC via MFMA + output transpose
    fc_mfma<<<dim3(BB, 7), 256, 0, stream>>>(h2, fc_w, fc_b, out);
}